// Round 6
// baseline (28.810 us; speedup 1.0000x reference)
//
#include <hip/hip_runtime.h>
#include <hip/hip_bf16.h>
#include <cstdint>
#include <climits>

#define HW 112
#define NPIX (HW*HW)   // 12544
#define NB 2
#define NC 4
#define HALF_ROWS 56
#define NWORK 24       // 12 (b,dir,class) pairs x 2 half-planes
#define QPP (NPIX/4)   // 3136 quads per plane

// ws: float2 partial[24] (sum,count) — written unconditionally each launch by
// mhd_main, read by fin. No atomics anywhere; cross-kernel visibility via the
// kernel-boundary release (same pattern as R3/R4, proven).
// Each block is fully self-contained: builds its own src/tgt masks + g^2 plane
// in LDS (inputs are tiny and L2-resident, redundant reads are ~free), so
// there is no prep kernel and no grid sync.

__device__ __forceinline__ unsigned argmax_bits(const float4* __restrict__ pp,
                                                int q, int j) {
  float4 v0 = pp[q], v1 = pp[q + QPP], v2 = pp[q + 2*QPP], v3 = pp[q + 3*QPP];
  unsigned bits = 0;
  { float bst=v0.x; int cl=0; if(v1.x>bst){bst=v1.x;cl=1;} if(v2.x>bst){bst=v2.x;cl=2;} if(v3.x>bst){cl=3;} bits |= (unsigned)(cl==j); }
  { float bst=v0.y; int cl=0; if(v1.y>bst){bst=v1.y;cl=1;} if(v2.y>bst){bst=v2.y;cl=2;} if(v3.y>bst){cl=3;} bits |= (unsigned)(cl==j)<<1; }
  { float bst=v0.z; int cl=0; if(v1.z>bst){bst=v1.z;cl=1;} if(v2.z>bst){bst=v2.z;cl=2;} if(v3.z>bst){cl=3;} bits |= (unsigned)(cl==j)<<2; }
  { float bst=v0.w; int cl=0; if(v1.w>bst){bst=v1.w;cl=1;} if(v2.w>bst){bst=v2.w;cl=2;} if(v3.w>bst){cl=3;} bits |= (unsigned)(cl==j)<<3; }
  return bits;
}

__global__ __launch_bounds__(1024) void mhd_main(
    const float* __restrict__ pred, const int* __restrict__ labels,
    float2* __restrict__ partial)
{
  __shared__ unsigned srcMask[HW][4];          // full-plane source bitmask
  __shared__ unsigned tgtMask[HALF_ROWS][4];   // this block's 56 target rows
  __shared__ unsigned short gsq[HW][HW];       // per-row horizontal dist^2
  __shared__ float red[32];

  int blk = blockIdx.x;
  int pd = blk >> 1, half = blk & 1;
  int b = pd / 6, k = pd % 6;
  int j = (k % 3) + 1;            // class 1..3
  bool isFwd = (k < 3);           // fwd: src=B(label), tgt=A(argmax); rev: swapped
  int tid = threadIdx.x, lane = tid & 63, wv = tid >> 6;
  int r0 = half * HALF_ROWS;

  if (tid < HW*4) ((unsigned*)srcMask)[tid] = 0;
  if (tid < HALF_ROWS*4) ((unsigned*)tgtMask)[tid] = 0;
  __syncthreads();

  // ---- build src mask (full plane) ----
  if (isFwd) {
    const int4* lp = (const int4*)(labels + ((size_t)(b*NC + j))*NPIX);
    for (int q = tid; q < QPP; q += 1024) {
      int4 v = lp[q];
      unsigned bits = (unsigned)(v.x==1) | ((unsigned)(v.y==1)<<1)
                    | ((unsigned)(v.z==1)<<2) | ((unsigned)(v.w==1)<<3);
      if (bits) { int p = q*4, r = p/HW, c = p%HW; atomicOr(&srcMask[r][c>>5], bits << (c&31)); }
    }
  } else {
    const float4* pp = (const float4*)(pred + (size_t)(b*NC)*NPIX);
    for (int q = tid; q < QPP; q += 1024) {
      unsigned bits = argmax_bits(pp, q, j);
      if (bits) { int p = q*4, r = p/HW, c = p%HW; atomicOr(&srcMask[r][c>>5], bits << (c&31)); }
    }
  }

  // ---- build tgt mask (this block's 56 rows) ----
  if (isFwd) {
    const float4* pp = (const float4*)(pred + (size_t)(b*NC)*NPIX + (size_t)r0*HW);
    for (int q = tid; q < HALF_ROWS*HW/4; q += 1024) {   // 1568
      unsigned bits = argmax_bits(pp, q, j);
      if (bits) { int p = q*4, r = p/HW, c = p%HW; atomicOr(&tgtMask[r][c>>5], bits << (c&31)); }
    }
  } else {
    const int4* lp = (const int4*)(labels + ((size_t)(b*NC + j))*NPIX + (size_t)r0*HW);
    for (int q = tid; q < HALF_ROWS*HW/4; q += 1024) {
      int4 v = lp[q];
      unsigned bits = (unsigned)(v.x==1) | ((unsigned)(v.y==1)<<1)
                    | ((unsigned)(v.z==1)<<2) | ((unsigned)(v.w==1)<<3);
      if (bits) { int p = q*4, r = p/HW, c = p%HW; atomicOr(&tgtMask[r][c>>5], bits << (c&31)); }
    }
  }
  __syncthreads();

  // ---- phase 1: per-row horizontal nearest-set distance -> g^2 (LDS) ----
  for (int it = tid; it < NPIX; it += 1024) {
    int r = it / HW, cc = it % HW;
    unsigned long long lo = srcMask[r][0] | ((unsigned long long)srcMask[r][1] << 32);
    unsigned long long hi = srcMask[r][2] | ((unsigned long long)srcMask[r][3] << 32);
    int left, right;
    if (cc < 64) {
      unsigned long long wl = lo & ((2ull << cc) - 1);
      left = wl ? 63 - __clzll(wl) : -1000;
      unsigned long long wr = lo & ~((1ull << cc) - 1);
      right = wr ? __ffsll(wr) - 1 : (hi ? 64 + __ffsll(hi) - 1 : 1000);
    } else {
      int cl = cc - 64;
      unsigned long long wl = hi & ((2ull << cl) - 1);
      left = wl ? 64 + 63 - __clzll(wl) : (lo ? 63 - __clzll(lo) : -1000);
      unsigned long long wr = hi & ~((1ull << cl) - 1);
      right = wr ? 64 + __ffsll(wr) - 1 : 1000;
    }
    int gv = min(min(cc - left, right - cc), 255);  // 255 sentinel: empty row
    gsq[r][cc] = (unsigned short)(gv*gv);
  }
  __syncthreads();

  // ---- phase 2: vertical min over 112 rows; 896 threads x 7 rows each ----
  int c  = tid % HW;          // 0..111
  int rg = tid / HW;          // 0..9; rg<8 active
  float sum = 0.f, cf = 0.f;
  if (rg < 8) {
    int rbase = r0 + rg*7;
    int m[7];
    #pragma unroll
    for (int i = 0; i < 7; i++) m[i] = INT_MAX;
    #pragma unroll 4
    for (int rp = 0; rp < HW; rp++) {
      int g2 = gsq[rp][c];
      int d0 = rbase - rp;
      #pragma unroll
      for (int i = 0; i < 7; i++) m[i] = min(m[i], __mul24(d0 + i, d0 + i) + g2);
    }
    #pragma unroll
    for (int i = 0; i < 7; i++) {
      int lr = rg*7 + i;
      if ((tgtMask[lr][c>>5] >> (c&31)) & 1u) { sum += sqrtf((float)m[i]); cf += 1.f; }
    }
  }

  #pragma unroll
  for (int off = 32; off; off >>= 1) {
    sum += __shfl_down(sum, off, 64);
    cf  += __shfl_down(cf, off, 64);
  }
  if (lane == 0) { red[wv*2] = sum; red[wv*2 + 1] = cf; }
  __syncthreads();
  if (tid == 0) {
    float S = 0.f, C = 0.f;
    #pragma unroll
    for (int w = 0; w < 16; w++) { S += red[w*2]; C += red[w*2 + 1]; }
    partial[blk] = make_float2(S, C);
  }
}

// 1 tiny block: reduce 24 partials (2 halves per pd), finalize 18 outputs.
__global__ __launch_bounds__(64) void fin_kernel(
    const float2* __restrict__ partial, float* __restrict__ out)
{
  int tid = threadIdx.x;
  __shared__ float sacc[24];
  if (tid < 12) {
    float2 p0 = partial[tid*2], p1 = partial[tid*2 + 1];
    sacc[tid] = p0.x + p1.x;
    sacc[12 + tid] = p0.y + p1.y;
  }
  __syncthreads();
  if (tid == 0) {
    float mhd[6], fhd[6], rhd[6];
    for (int i = 0; i < 6; i++) { mhd[i] = 0.f; fhd[i] = 0.f; rhd[i] = 0.f; }
    for (int bb = 0; bb < 2; bb++)
      for (int j = 1; j < 4; j++) {
        int pf = bb*6 + (j - 1);
        int pr = bb*6 + 3 + (j - 1);
        float fwd = sacc[pf] / sacc[12 + pf];
        float rev = sacc[pr] / sacc[12 + pr];
        fhd[j] += fwd; rhd[j] += rev; mhd[j] += fmaxf(fwd, rev);
      }
    float* arrs[3] = { mhd, fhd, rhd };
    for (int a = 0; a < 3; a++) {
      float* x = arrs[a];
      for (int i = 0; i < 4; i++) x[i] *= 0.5f;          // /N
      x[4] = (x[0] + x[1] + x[2] + x[3]) * 0.25f;        // mean(x[:C])
      x[5] = (x[1] + x[2] + x[3]) * (1.f / 3.f);         // mean(x[1:C])
      for (int i = 0; i < 6; i++) out[a*6 + i] = x[i];
    }
  }
}

extern "C" void kernel_launch(void* const* d_in, const int* in_sizes, int n_in,
                              void* d_out, int out_size, void* d_ws, size_t ws_size,
                              hipStream_t stream) {
  const float* pred = (const float*)d_in[0];
  const int* labels = (const int*)d_in[1];
  float* out = (float*)d_out;
  float2* partial = (float2*)d_ws;

  mhd_main<<<NWORK, 1024, 0, stream>>>(pred, labels, partial);
  fin_kernel<<<1, 64, 0, stream>>>(partial, out);
}

// Round 7
// 14.825 us; speedup vs baseline: 1.9434x; 1.9434x over previous
//
#include <hip/hip_runtime.h>
#include <hip/hip_bf16.h>
#include <cstdint>
#include <climits>

#define HW 112
#define NPIX (HW*HW)   // 12544
#define NB 2
#define NC 4
#define CHUNKS 28                  // chunks per (pair,dir); 4 rows each
#define HD_GRID (12*CHUNKS)        // 336

// ws layout:
//   +0:       packed masks  uint64_t[12 masks][112 rows][2 words]   (21504 B)
//   +21504:   g^2 planes    uint16_t[12 planes][12544]              (301056 B)
//   +322560:  partials      float2[336]  (sum, count) per hd block
// mask id = b*6 + m, m=0..2 -> A(j=m+1) (argmax==j), m=3..5 -> B(j=m-2) (label==1)

__global__ __launch_bounds__(128) void prep_kernel(
    const float* __restrict__ pred, const int* __restrict__ labels,
    unsigned long long* __restrict__ masks, unsigned short* __restrict__ gsqbuf)
{
  int blk = blockIdx.x;
  int b = blk / HW, r = blk % HW;
  int tid = threadIdx.x;
  int lane = tid & 63, wave = tid >> 6;
  int c = tid;

  int cls = 255;
  if (c < HW) {
    const float* p0 = pred + ((size_t)(b*NC)*HW + r)*HW + c;
    float best = p0[0]; cls = 0;
    #pragma unroll
    for (int ch = 1; ch < NC; ch++) {
      float v = p0[(size_t)ch*NPIX];
      if (v > best) { best = v; cls = ch; }   // strict > : first-index tie-break like argmax
    }
  }

  __shared__ unsigned long long sm[6][2];
  #pragma unroll
  for (int m = 0; m < 3; m++) {
    bool p = (c < HW) && (cls == m + 1);
    unsigned long long bal = __ballot(p);
    if (lane == 0) sm[m][wave] = bal;
  }
  #pragma unroll
  for (int m = 0; m < 3; m++) {
    int lab = (c < HW) ? labels[((size_t)(b*NC + (m+1))*HW + r)*HW + c] : 0;
    bool p = (c < HW) && (lab == 1);
    unsigned long long bal = __ballot(p);
    if (lane == 0) sm[3 + m][wave] = bal;
  }
  __syncthreads();

  if (tid < 12) {
    int m = tid >> 1, w = tid & 1;
    masks[((size_t)(b*6 + m)*HW + r)*2 + w] = sm[m][w];
  }

  // phase 1: horizontal nearest-set-pixel distance, O(1)/pixel via clz/ffs;
  // store g^2 as ushort
  for (int item = tid; item < 6*HW; item += 128) {
    int m = item / HW, cc = item % HW;
    unsigned long long lo = sm[m][0], hi = sm[m][1];
    int left, right;
    if (cc < 64) {
      unsigned long long wl = lo & ((2ull << cc) - 1);           // bits 0..cc
      left = wl ? 63 - __clzll(wl) : -1000;
      unsigned long long wr = lo & ~((1ull << cc) - 1);          // bits cc..63
      right = wr ? __ffsll(wr) - 1 : (hi ? 64 + __ffsll(hi) - 1 : 1000);
    } else {
      int cl = cc - 64;
      unsigned long long wl = hi & ((2ull << cl) - 1);           // bits 64..cc
      left = wl ? 64 + 63 - __clzll(wl) : (lo ? 63 - __clzll(lo) : -1000);
      unsigned long long wr = hi & ~((1ull << cl) - 1);          // bits cc..111
      right = wr ? 64 + __ffsll(wr) - 1 : 1000;
    }
    int gv = min(min(cc - left, right - cc), 255);  // 255 sentinel: empty row
    gsqbuf[(size_t)(b*6 + m)*NPIX + r*HW + cc] = (unsigned short)(gv*gv);
  }
}

// one block per (pair-dir, 4-row chunk), 128 threads (columns). Early-exit
// vertical scan: best = min over d of d^2 + g2[r+-d]; once d^2 >= best no
// farther row can win. d<=2 handled branch-free from an 8-row register
// window (independent coalesced loads, L1/L2-hit); rare tail loop for
// best > 9. Extra unconditional candidates are valid distances -> exact.
__global__ __launch_bounds__(128) void hd_kernel(
    const unsigned long long* __restrict__ masks,
    const unsigned short* __restrict__ gsqbuf,
    float2* __restrict__ partial)
{
  int blk = blockIdx.x;
  int pd = blk / CHUNKS, chunk = blk % CHUNKS;
  int b = pd / 6, k = pd % 6;
  // k<3: fwd for j=k+1 (src plane = B mask, target = A mask)
  // k>=3: rev for j=k-2 (src plane = A mask, target = B mask)
  int src = b*6 + (k + 3) % 6;
  int tid = threadIdx.x, lane = tid & 63, wv = tid >> 6;
  int c = tid;
  int r0 = chunk * 4;

  float sum = 0.f, cf = 0.f;
  if (c < HW) {
    const unsigned short* g2p = gsqbuf + (size_t)src*NPIX + c;

    // 8-row register window: rows r0-2 .. r0+5 (guarded), all independent loads
    int w[8];
    #pragma unroll
    for (int t = 0; t < 8; t++) {
      int gr = r0 - 2 + t;
      w[t] = (gr >= 0 && gr < HW) ? (int)g2p[(size_t)gr*HW] : 0x7fff;
    }

    #pragma unroll
    for (int i = 0; i < 4; i++) {
      int r = r0 + i;
      int best = w[i + 2];                                  // d=0
      best = min(best, 1 + min(w[i + 1], w[i + 3]));        // d=1
      best = min(best, 4 + min(w[i],     w[i + 4]));        // d=2
      if (best > 9) {                                       // rare tail
        for (int d = 3; d < HW; d++) {
          int dd = d*d;
          if (dd >= best) break;
          int ru = r - d, rd = r + d;
          if (ru >= 0)  best = min(best, dd + (int)g2p[(size_t)ru*HW]);
          if (rd < HW)  best = min(best, dd + (int)g2p[(size_t)rd*HW]);
        }
      }
      unsigned long long wm = masks[((size_t)pd*HW + r)*2 + (c >> 6)];
      if ((wm >> (c & 63)) & 1ull) { sum += sqrtf((float)best); cf += 1.f; }
    }
  }

  #pragma unroll
  for (int off = 32; off; off >>= 1) {
    sum += __shfl_down(sum, off, 64);
    cf  += __shfl_down(cf, off, 64);
  }
  __shared__ float red[4];
  if (lane == 0) { red[wv*2] = sum; red[wv*2 + 1] = cf; }
  __syncthreads();
  if (tid == 0) partial[blk] = make_float2(red[0] + red[2], red[1] + red[3]);
}

// 12 waves, one per (b,dir,class): deterministic shuffle-reduce of 28 partials,
// then thread 0 finalizes the 18 outputs.
__global__ __launch_bounds__(768) void fin_kernel(
    const float2* __restrict__ partial, float* __restrict__ out)
{
  int tid = threadIdx.x;
  int w = tid >> 6, lane = tid & 63;
  __shared__ float sacc[24];

  float s = 0.f, cnt = 0.f;
  if (lane < CHUNKS) {
    float2 p = partial[w*CHUNKS + lane];
    s = p.x; cnt = p.y;
  }
  #pragma unroll
  for (int off = 32; off; off >>= 1) {
    s   += __shfl_down(s, off, 64);
    cnt += __shfl_down(cnt, off, 64);
  }
  if (lane == 0) { sacc[w] = s; sacc[12 + w] = cnt; }
  __syncthreads();

  if (tid == 0) {
    float mhd[6], fhd[6], rhd[6];
    for (int i = 0; i < 6; i++) { mhd[i] = 0.f; fhd[i] = 0.f; rhd[i] = 0.f; }
    for (int bb = 0; bb < 2; bb++)
      for (int j = 1; j < 4; j++) {
        int pf = bb*6 + (j - 1);
        int pr = bb*6 + 3 + (j - 1);
        float fwd = sacc[pf] / sacc[12 + pf];
        float rev = sacc[pr] / sacc[12 + pr];
        fhd[j] += fwd; rhd[j] += rev; mhd[j] += fmaxf(fwd, rev);
      }
    float* arrs[3] = { mhd, fhd, rhd };
    for (int a = 0; a < 3; a++) {
      float* x = arrs[a];
      for (int i = 0; i < 4; i++) x[i] *= 0.5f;          // /N
      x[4] = (x[0] + x[1] + x[2] + x[3]) * 0.25f;        // mean(x[:C])
      x[5] = (x[1] + x[2] + x[3]) * (1.f / 3.f);         // mean(x[1:C])
      for (int i = 0; i < 6; i++) out[a*6 + i] = x[i];
    }
  }
}

extern "C" void kernel_launch(void* const* d_in, const int* in_sizes, int n_in,
                              void* d_out, int out_size, void* d_ws, size_t ws_size,
                              hipStream_t stream) {
  const float* pred = (const float*)d_in[0];
  const int* labels = (const int*)d_in[1];
  float* out = (float*)d_out;

  unsigned long long* masks = (unsigned long long*)d_ws;
  unsigned short* gsqbuf = (unsigned short*)((char*)d_ws + 21504);
  float2* partial = (float2*)((char*)d_ws + 21504 + (size_t)12*NPIX*sizeof(unsigned short));

  prep_kernel<<<NB*HW, 128, 0, stream>>>(pred, labels, masks, gsqbuf);
  hd_kernel<<<HD_GRID, 128, 0, stream>>>(masks, gsqbuf, partial);
  fin_kernel<<<1, 768, 0, stream>>>(partial, out);
}